// Round 2
// baseline (2021.664 us; speedup 1.0000x reference)
//
#include <hip/hip_runtime.h>
#include <math.h>

#ifndef M_PI
#define M_PI 3.14159265358979323846
#endif

#define NGRID 513
#define NCELL 512
#define NINT  511
#define NB    4

constexpr int N2G = NGRID * NGRID;   // 263169
constexpr int NI2 = NINT * NINT;     // 261121
constexpr int NTT = NGRID * NINT;    // 262143

// ---------------------------------------------------------------------------
// FEM Darcy operator at interior node (i,j), i,j in 1..511
// ---------------------------------------------------------------------------
__device__ __forceinline__ float darcyA(const float* __restrict__ x,
                                        const float* __restrict__ a,
                                        int i, int j) {
    const float c23 = 2.0f / 3.0f, c16 = 1.0f / 6.0f, c13 = 1.0f / 3.0f;
    float a00 = a[(i - 1) * NCELL + (j - 1)];
    float a01 = a[(i - 1) * NCELL + j];
    float a10 = a[i * NCELL + (j - 1)];
    float a11 = a[i * NCELL + j];
    const float* xm = x + (i - 1) * NGRID;
    const float* xc = x + i * NGRID;
    const float* xp = x + (i + 1) * NGRID;
    return c23 * (a00 + a01 + a10 + a11) * xc[j]
         - c16 * ((a00 + a01) * xm[j] + (a10 + a11) * xp[j]
                + (a00 + a10) * xc[j - 1] + (a01 + a11) * xc[j + 1])
         - c13 * (a00 * xm[j - 1] + a01 * xm[j + 1]
                + a10 * xp[j - 1] + a11 * xp[j + 1]);
}

// mode 0: out = f - A x   (boundary: out = f)
// mode 1: out = x + 0.75*dinv*(f - A x)  (boundary: out = x)
// mode 2: out = A x       (boundary: out = 0)
__global__ void k_stencil(const float* __restrict__ xin,
                          const float* __restrict__ a,
                          const float* __restrict__ f,
                          const float* __restrict__ dinv,
                          float* __restrict__ out, int mode) {
    int b = blockIdx.z;
    int j = blockIdx.x * 16 + threadIdx.x;
    int i = blockIdx.y * 16 + threadIdx.y;
    if (i >= NGRID || j >= NGRID) return;
    const float* xb = xin + (long long)b * N2G;
    const float* ab = a + (long long)b * NCELL * NCELL;
    long long idx = (long long)b * N2G + (long long)i * NGRID + j;
    bool interior = (i >= 1 && i <= NINT && j >= 1 && j <= NINT);
    if (!interior) {
        out[idx] = (mode == 0) ? f[idx] : (mode == 1 ? xb[i * NGRID + j] : 0.0f);
        return;
    }
    float Ax = darcyA(xb, ab, i, j);
    if (mode == 0) {
        out[idx] = f[idx] - Ax;
    } else if (mode == 1) {
        float di = dinv[(long long)b * NI2 + (i - 1) * NINT + (j - 1)];
        out[idx] = xb[i * NGRID + j] + 0.75f * di * (f[idx] - Ax);
    } else {
        out[idx] = Ax;
    }
}

__global__ void k_dinv(const float* __restrict__ a, float* __restrict__ dinv) {
    long long idx = (long long)blockIdx.x * blockDim.x + threadIdx.x;
    if (idx >= (long long)NB * NI2) return;
    int b = (int)(idx / NI2);
    int rem = (int)(idx % NI2);
    int p = rem / NINT, q = rem % NINT;
    const float* ab = a + (long long)b * NCELL * NCELL;
    float s = ab[p * NCELL + q] + ab[p * NCELL + q + 1]
            + ab[(p + 1) * NCELL + q] + ab[(p + 1) * NCELL + q + 1];
    dinv[idx] = 1.0f / ((2.0f / 3.0f) * s);
}

// ---------------------------------------------------------------------------
// Twiddle generation (integer argument reduction -> double sin/cos -> fp32)
// ---------------------------------------------------------------------------
// G[u][n]  = sin(pi*(u-256)*(n+1)/512)              (513 x 511)
// Gt[n][v] = sin(pi*(v-256)*(n+1)/512) * (-1/512^2) (511 x 513)
__global__ void k_gen_dst(float* __restrict__ G, float* __restrict__ Gt) {
    int idx = blockIdx.x * blockDim.x + threadIdx.x;
    if (idx >= NGRID * NINT) return;
    int u = idx / NINT, n = idx % NINT;
    int k = u - 256, nn = n + 1;
    int t = (k * nn) % 1024;
    if (t < 0) t += 1024;
    float s = (float)sin((M_PI / 512.0) * (double)t);
    G[idx] = s;
    Gt[n * NGRID + u] = s * (-1.0f / 262144.0f);
}

// F[y][m]  = exp(-2*pi*i*y*(m-255)/1025)  (511 x 513), Ft = F^T (513 x 511)
__global__ void k_gen_dft(float* __restrict__ Fr, float* __restrict__ Fi,
                          float* __restrict__ Ftr, float* __restrict__ Fti) {
    int idx = blockIdx.x * blockDim.x + threadIdx.x;
    if (idx >= NINT * NGRID) return;
    int y = idx / NGRID, m = idx % NGRID;
    long t = ((long)y * (m - 255)) % 1025;
    if (t < 0) t += 1025;
    double ang = (2.0 * M_PI / 1025.0) * (double)t;
    float cr = (float)cos(ang);
    float ci = (float)(-sin(ang));
    Fr[idx] = cr;
    Fi[idx] = ci;
    Ftr[m * NINT + y] = cr;
    Fti[m * NINT + y] = ci;
}

// ---------------------------------------------------------------------------
// Tiled (complex) GEMM with split-K + atomicAdd epilogue.
// C[M,N] += A[M,K] * B[K,N], planar re/im. C MUST be zeroed before launch.
// MODE 0: real*real->real ; 1: cplx*cplx->cplx ; 2: cplx*cplx->real-part-only
// 64x64 tile, 16x16 threads, 4x4 per thread, K-tile 32.
// gridDim.z = NB * nsplit.
// ---------------------------------------------------------------------------
template <int MODE>
__global__ __launch_bounds__(256) void k_zgemm(
    const float* __restrict__ Ar, const float* __restrict__ Ai, int lda, long long bsA,
    const float* __restrict__ Br, const float* __restrict__ Bi, int ldb, long long bsB,
    float* __restrict__ Cr, float* __restrict__ Ci, int ldc, long long bsC,
    int M, int N, int K, int nsplit) {
    __shared__ __align__(16) float As_r[32][68];
    __shared__ __align__(16) float Bs_r[32][68];
    __shared__ __align__(16) float As_i[MODE ? 32 : 1][68];
    __shared__ __align__(16) float Bs_i[MODE ? 32 : 1][68];

    int bz = blockIdx.z;
    int b = bz / nsplit;
    int ks = bz % nsplit;
    int kchunk = (K + nsplit - 1) / nsplit;
    int kbeg = ks * kchunk;
    int kend = min(K, kbeg + kchunk);

    Ar += b * bsA; Br += b * bsB; Cr += b * bsC;
    if (MODE) { Ai += b * bsA; Bi += b * bsB; }
    if (MODE == 1) Ci += b * bsC;

    int bm = blockIdx.y * 64, bn = blockIdx.x * 64;
    int tid = threadIdx.x;
    int ty = tid >> 4, tx = tid & 15;

    float cr[4][4] = {};
    float cim[4][4] = {};

    for (int kt = kbeg; kt < kend; kt += 32) {
        // stage A tile as [k][m]: thread -> m = tid>>2 (64), k0 = (tid&3)*8
        int m = tid >> 2, k0 = (tid & 3) * 8;
        int gm = bm + m;
        #pragma unroll
        for (int c = 0; c < 8; ++c) {
            int gk = kt + k0 + c;
            bool in = (gm < M) && (gk < kend);
            As_r[k0 + c][m] = in ? Ar[(long long)gm * lda + gk] : 0.0f;
            if (MODE) As_i[k0 + c][m] = in ? Ai[(long long)gm * lda + gk] : 0.0f;
        }
        // stage B tile as [k][n]: thread -> kb = tid>>3 (32), n0 = (tid&7)*8
        int kb = tid >> 3, n0 = (tid & 7) * 8;
        int gk2 = kt + kb;
        #pragma unroll
        for (int c = 0; c < 8; ++c) {
            int gn = bn + n0 + c;
            bool in = (gk2 < kend) && (gn < N);
            Bs_r[kb][n0 + c] = in ? Br[(long long)gk2 * ldb + gn] : 0.0f;
            if (MODE) Bs_i[kb][n0 + c] = in ? Bi[(long long)gk2 * ldb + gn] : 0.0f;
        }
        __syncthreads();
        #pragma unroll
        for (int kk = 0; kk < 32; ++kk) {
            float4 arv = *(const float4*)&As_r[kk][ty * 4];
            float4 brv = *(const float4*)&Bs_r[kk][tx * 4];
            float ar[4] = {arv.x, arv.y, arv.z, arv.w};
            float br[4] = {brv.x, brv.y, brv.z, brv.w};
            if (MODE) {
                float4 aiv = *(const float4*)&As_i[kk][ty * 4];
                float4 biv = *(const float4*)&Bs_i[kk][tx * 4];
                float ai[4] = {aiv.x, aiv.y, aiv.z, aiv.w};
                float bi[4] = {biv.x, biv.y, biv.z, biv.w};
                #pragma unroll
                for (int i2 = 0; i2 < 4; ++i2)
                    #pragma unroll
                    for (int j2 = 0; j2 < 4; ++j2) {
                        cr[i2][j2] += ar[i2] * br[j2] - ai[i2] * bi[j2];
                        if (MODE == 1) cim[i2][j2] += ar[i2] * bi[j2] + ai[i2] * br[j2];
                    }
            } else {
                #pragma unroll
                for (int i2 = 0; i2 < 4; ++i2)
                    #pragma unroll
                    for (int j2 = 0; j2 < 4; ++j2)
                        cr[i2][j2] += ar[i2] * br[j2];
            }
        }
        __syncthreads();
    }

    #pragma unroll
    for (int i2 = 0; i2 < 4; ++i2) {
        int gm = bm + ty * 4 + i2;
        if (gm >= M) continue;
        #pragma unroll
        for (int j2 = 0; j2 < 4; ++j2) {
            int gn = bn + tx * 4 + j2;
            if (gn >= N) continue;
            atomicAdd(&Cr[(long long)gm * ldc + gn], cr[i2][j2]);
            if (MODE == 1) atomicAdd(&Ci[(long long)gm * ldc + gn], cim[i2][j2]);
        }
    }
}

// ---------------------------------------------------------------------------
// Complex multi-channel 3x3 conv (cross-correlation, zero pad 1), per-batch
// weights. conjt: use w[b][ci][co][q][p] and conjugate (== mcc with conjT(w)).
// ---------------------------------------------------------------------------
template <int CIN, int COUT, bool INC>
__global__ __launch_bounds__(256) void k_mcc(
    const float* __restrict__ xr, const float* __restrict__ xi,
    const float* __restrict__ wr, const float* __restrict__ wi,
    float* __restrict__ yr, float* __restrict__ yi,
    int wb, int ws1, int ws2, int conjt) {
    __shared__ float tile[CIN][2][18][18];
    __shared__ float wl[COUT * CIN * 18];
    int b = blockIdx.z;
    int tid = threadIdx.y * 16 + threadIdx.x;

    for (int idx = tid; idx < COUT * CIN * 9; idx += 256) {
        int co = idx / (CIN * 9);
        int r2 = idx % (CIN * 9);
        int ci = r2 / 9, s = r2 % 9;
        int p = s / 3, q = s % 3;
        int widx = conjt ? (b * wb + ci * ws1 + co * ws2 + q * 3 + p)
                         : (b * wb + co * ws1 + ci * ws2 + p * 3 + q);
        wl[idx * 2] = wr[widx];
        float iv = wi[widx];
        wl[idx * 2 + 1] = conjt ? -iv : iv;
    }
    int ox = blockIdx.x * 16, oy = blockIdx.y * 16;
    for (int idx = tid; idx < CIN * 18 * 18; idx += 256) {
        int ci = idx / 324, r2 = idx % 324;
        int ly = r2 / 18, lx = r2 % 18;
        int gy = oy + ly - 1, gx = ox + lx - 1;
        bool in = (gy >= 0 && gy < NGRID && gx >= 0 && gx < NGRID);
        long long gi = (long long)(b * CIN + ci) * N2G + (long long)gy * NGRID + gx;
        tile[ci][0][ly][lx] = in ? xr[gi] : 0.0f;
        if (INC) tile[ci][1][ly][lx] = in ? xi[gi] : 0.0f;
    }
    __syncthreads();

    int tx = threadIdx.x, ty = threadIdx.y;
    int gx = ox + tx, gy = oy + ty;
    float accr[COUT], acci[COUT];
    #pragma unroll
    for (int co = 0; co < COUT; ++co) { accr[co] = 0.0f; acci[co] = 0.0f; }

    #pragma unroll
    for (int ci = 0; ci < CIN; ++ci)
        #pragma unroll
        for (int p = 0; p < 3; ++p)
            #pragma unroll
            for (int q = 0; q < 3; ++q) {
                float xrv = tile[ci][0][ty + p][tx + q];
                float xiv = INC ? tile[ci][1][ty + p][tx + q] : 0.0f;
                #pragma unroll
                for (int co = 0; co < COUT; ++co) {
                    float wrv = wl[((co * CIN + ci) * 9 + p * 3 + q) * 2];
                    float wiv = wl[((co * CIN + ci) * 9 + p * 3 + q) * 2 + 1];
                    if (INC) {
                        accr[co] += wrv * xrv - wiv * xiv;
                        acci[co] += wrv * xiv + wiv * xrv;
                    } else {
                        accr[co] += wrv * xrv;
                        acci[co] += wiv * xrv;
                    }
                }
            }

    if (gy < NGRID && gx < NGRID) {
        #pragma unroll
        for (int co = 0; co < COUT; ++co) {
            long long gi = (long long)(b * COUT + co) * N2G + (long long)gy * NGRID + gx;
            yr[gi] = accr[co];
            yi[gi] = acci[co];
        }
    }
}

// o *= wt * ik2  (complex multiply by wt, scale by ik2)
__global__ void k_scale(float* __restrict__ or_, float* __restrict__ oi_,
                        const float* __restrict__ wtr, const float* __restrict__ wti) {
    long long idx = (long long)blockIdx.x * blockDim.x + threadIdx.x;
    if (idx >= (long long)NB * N2G) return;
    int pix = (int)(idx % N2G);
    int u = pix / NGRID, v = pix % NGRID;
    int du = u - 256, dv = v - 256;
    float ik2;
    if (du == 0 && dv == 0)
        ik2 = 1.0f;
    else
        ik2 = (float)(1.0 / (9.869604401089358 * (double)(du * du + dv * dv)));
    float xr = or_[idx], xv = oi_[idx];
    float wrv = wtr[idx], wiv = wti[idx];
    or_[idx] = (xr * wrv - xv * wiv) * ik2;
    oi_[idx] = (xr * wiv + xv * wrv) * ik2;
}

// per-batch: red[2b] += sum(r*e), red[2b+1] += sum(Ae*e)
__global__ void k_dot2(const float* __restrict__ r, const float* __restrict__ e,
                       const float* __restrict__ Ae, float* __restrict__ red) {
    int b = blockIdx.y;
    const float* rb = r + (long long)b * N2G;
    const float* eb = e + (long long)b * N2G;
    const float* ab = Ae + (long long)b * N2G;
    float s1 = 0.0f, s2 = 0.0f;
    for (int i = blockIdx.x * blockDim.x + threadIdx.x; i < N2G;
         i += gridDim.x * blockDim.x) {
        float ev = eb[i];
        s1 += rb[i] * ev;
        s2 += ab[i] * ev;
    }
    #pragma unroll
    for (int o = 32; o > 0; o >>= 1) {
        s1 += __shfl_down(s1, o);
        s2 += __shfl_down(s2, o);
    }
    __shared__ float l1[4], l2[4];
    int wid = threadIdx.x >> 6;
    if ((threadIdx.x & 63) == 0) { l1[wid] = s1; l2[wid] = s2; }
    __syncthreads();
    if (threadIdx.x == 0) {
        atomicAdd(&red[2 * b], l1[0] + l1[1] + l1[2] + l1[3]);
        atomicAdd(&red[2 * b + 1], l2[0] + l2[1] + l2[2] + l2[3]);
    }
}

__global__ void k_update(float* __restrict__ x, const float* __restrict__ e,
                         const float* __restrict__ red) {
    long long idx = (long long)blockIdx.x * blockDim.x + threadIdx.x;
    if (idx >= (long long)NB * N2G) return;
    int b = (int)(idx / N2G);
    float alpha = red[2 * b] / red[2 * b + 1];
    x[idx] += alpha * e[idx];
}

__global__ void k_norm(const float* __restrict__ r, const float* __restrict__ f,
                       float* __restrict__ red) {
    float s1 = 0.0f, s2 = 0.0f;
    for (long long i = (long long)blockIdx.x * blockDim.x + threadIdx.x;
         i < (long long)NB * N2G; i += (long long)gridDim.x * blockDim.x) {
        float rv = r[i], fv = f[i];
        s1 += rv * rv;
        s2 += fv * fv;
    }
    #pragma unroll
    for (int o = 32; o > 0; o >>= 1) {
        s1 += __shfl_down(s1, o);
        s2 += __shfl_down(s2, o);
    }
    __shared__ float l1[4], l2[4];
    int wid = threadIdx.x >> 6;
    if ((threadIdx.x & 63) == 0) { l1[wid] = s1; l2[wid] = s2; }
    __syncthreads();
    if (threadIdx.x == 0) {
        atomicAdd(&red[8], l1[0] + l1[1] + l1[2] + l1[3]);
        atomicAdd(&red[9], l2[0] + l2[1] + l2[2] + l2[3]);
    }
}

__global__ void k_final(const float* __restrict__ red, float* __restrict__ out) {
    out[0] = sqrtf(red[8] / red[9]);
}

// ---------------------------------------------------------------------------
extern "C" void kernel_launch(void* const* d_in, const int* in_sizes, int n_in,
                              void* d_out, int out_size, void* d_ws, size_t ws_size,
                              hipStream_t stream) {
    (void)in_sizes; (void)n_in; (void)out_size; (void)ws_size;
    const float* f    = (const float*)d_in[0];
    const float* coef = (const float*)d_in[1];
    const float* w1r  = (const float*)d_in[3];
    const float* w1i  = (const float*)d_in[4];
    const float* w2r  = (const float*)d_in[5];
    const float* w2i  = (const float*)d_in[6];
    const float* w3r  = (const float*)d_in[7];
    const float* w3i  = (const float*)d_in[8];
    const float* wtr  = (const float*)d_in[9];
    const float* wti  = (const float*)d_in[10];
    float* out = (float*)d_out;

    float* ws = (float*)d_ws;
    size_t off = 0;
    auto alloc = [&](long long n) {
        float* p = ws + off;
        off += (size_t)((n + 3) & ~3LL);
        return p;
    };
    float* x0   = alloc((long long)NB * N2G);
    float* x1   = alloc((long long)NB * N2G);
    float* rr   = alloc((long long)NB * N2G);
    float* ee   = alloc((long long)NB * N2G);
    float* rh   = alloc((long long)NB * N2G);
    float* dinv = alloc((long long)NB * NI2);
    float* c1r  = alloc((long long)NB * 4 * N2G);
    float* c1i  = alloc((long long)NB * 4 * N2G);
    float* c2r  = alloc((long long)NB * 4 * N2G);
    float* c2i  = alloc((long long)NB * 4 * N2G);
    float* or_  = alloc((long long)NB * N2G);
    float* oi_  = alloc((long long)NB * N2G);
    float* t2r  = alloc((long long)NB * NTT);
    float* t2i  = alloc((long long)NB * NTT);
    float* G    = alloc((long long)NGRID * NINT);
    float* Gt   = alloc((long long)NINT * NGRID);
    float* Fr   = alloc((long long)NINT * NGRID);
    float* Fi   = alloc((long long)NINT * NGRID);
    float* Ftr  = alloc((long long)NGRID * NINT);
    float* Fti  = alloc((long long)NGRID * NINT);
    float* red  = alloc(16);
    float* Ae   = x1;  // ping buffer is free when Ae is needed (10 sweeps = even)

    dim3 blk2(16, 16);
    dim3 grdS(33, 33, NB);
    const int SPLIT = 4;  // split-K factor: 288 -> 1152 blocks per zgemm

    auto zeroF = [&](float* p, long long n) {
        hipMemsetAsync(p, 0, (size_t)n * sizeof(float), stream);
    };

    zeroF(x0, (long long)NB * N2G);
    k_dinv<<<dim3((NB * NI2 + 255) / 256), dim3(256), 0, stream>>>(coef, dinv);
    k_gen_dst<<<dim3((NGRID * NINT + 255) / 256), dim3(256), 0, stream>>>(G, Gt);
    k_gen_dft<<<dim3((NINT * NGRID + 255) / 256), dim3(256), 0, stream>>>(Fr, Fi, Ftr, Fti);

    float* xa = x0;
    float* xb = x1;
    for (int step = 0; step < 2; ++step) {
        // 10 weighted-Jacobi sweeps (ping-pong)
        for (int it = 0; it < 10; ++it) {
            k_stencil<<<grdS, blk2, 0, stream>>>(xa, coef, f, dinv, xb, 1);
            float* t = xa; xa = xb; xb = t;
        }
        // residual
        k_stencil<<<grdS, blk2, 0, stream>>>(xa, coef, f, nullptr, rr, 0);

        // ---- H_apply ----
        // rh = -(1/512^2) * G * r_I * G^T (2-D DST == ifft2 of odd extension)
        zeroF(t2r, (long long)NB * NTT);
        k_zgemm<0><<<dim3(8, 9, NB * SPLIT), dim3(256), 0, stream>>>(
            G, nullptr, NINT, 0,
            rr + NGRID + 1, nullptr, NGRID, (long long)N2G,
            t2r, nullptr, NINT, (long long)NTT,
            NGRID, NINT, NINT, SPLIT);
        zeroF(rh, (long long)NB * N2G);
        k_zgemm<0><<<dim3(9, 9, NB * SPLIT), dim3(256), 0, stream>>>(
            t2r, nullptr, NINT, (long long)NTT,
            Gt, nullptr, NGRID, 0,
            rh, nullptr, NGRID, (long long)N2G,
            NGRID, NGRID, NINT, SPLIT);
        // forward convs: w1 (1->4), w2 (4->4), w3 (4->1)
        k_mcc<1, 4, false><<<grdS, blk2, 0, stream>>>(rh, nullptr, w1r, w1i, c1r, c1i, 36, 9, 9, 0);
        k_mcc<4, 4, true><<<grdS, blk2, 0, stream>>>(c1r, c1i, w2r, w2i, c2r, c2i, 144, 36, 9, 0);
        k_mcc<4, 1, true><<<grdS, blk2, 0, stream>>>(c2r, c2i, w3r, w3i, or_, oi_, 36, 36, 9, 0);
        // * wt * ik2
        k_scale<<<dim3((NB * N2G + 255) / 256), dim3(256), 0, stream>>>(or_, oi_, wtr, wti);
        // adjoint convs: conjT(w3) (1->4), conjT(w2) (4->4), conjT(w1) (4->1)
        k_mcc<1, 4, true><<<grdS, blk2, 0, stream>>>(or_, oi_, w3r, w3i, c1r, c1i, 36, 36, 9, 1);
        k_mcc<4, 4, true><<<grdS, blk2, 0, stream>>>(c1r, c1i, w2r, w2i, c2r, c2i, 144, 36, 9, 1);
        k_mcc<4, 1, true><<<grdS, blk2, 0, stream>>>(c2r, c2i, w1r, w1i, or_, oi_, 36, 9, 9, 1);
        // e_int = Re( F * O * F^T )  (the 1025-point fft2 of ifftshifted pad)
        zeroF(t2r, (long long)NB * NTT);
        zeroF(t2i, (long long)NB * NTT);
        k_zgemm<1><<<dim3(8, 9, NB * SPLIT), dim3(256), 0, stream>>>(
            or_, oi_, NGRID, (long long)N2G,
            Ftr, Fti, NINT, 0,
            t2r, t2i, NINT, (long long)NTT,
            NGRID, NINT, NGRID, SPLIT);
        zeroF(ee, (long long)NB * N2G);
        k_zgemm<2><<<dim3(8, 8, NB * SPLIT), dim3(256), 0, stream>>>(
            Fr, Fi, NGRID, 0,
            t2r, t2i, NINT, (long long)NTT,
            ee + NGRID + 1, nullptr, NGRID, (long long)N2G,
            NINT, NINT, NGRID, SPLIT);

        // Ae = A e ; alpha = (r.e)/(Ae.e) ; x += alpha e
        k_stencil<<<grdS, blk2, 0, stream>>>(ee, coef, nullptr, nullptr, Ae, 2);
        hipMemsetAsync(red, 0, 8 * sizeof(float), stream);
        k_dot2<<<dim3(64, NB), dim3(256), 0, stream>>>(rr, ee, Ae, red);
        k_update<<<dim3((NB * N2G + 255) / 256), dim3(256), 0, stream>>>(xa, ee, red);
    }
    // final relative residual norm
    k_stencil<<<grdS, blk2, 0, stream>>>(xa, coef, f, nullptr, rr, 0);
    hipMemsetAsync(red + 8, 0, 2 * sizeof(float), stream);
    k_norm<<<dim3(256), dim3(256), 0, stream>>>(rr, f, red);
    k_final<<<dim3(1), dim3(1), 0, stream>>>(red, out);
}

// Round 3
// 1589.612 us; speedup vs baseline: 1.2718x; 1.2718x over previous
//
#include <hip/hip_runtime.h>
#include <math.h>

#ifndef M_PI
#define M_PI 3.14159265358979323846
#endif

#define NGRID 513
#define NCELL 512
#define NINT  511
#define NB    4

constexpr int N2G = NGRID * NGRID;   // 263169
constexpr int NI2 = NINT * NINT;     // 261121
constexpr int NTT = NGRID * NINT;    // 262143

// ---------------------------------------------------------------------------
// FEM Darcy operator at interior node (i,j), i,j in 1..511
// ---------------------------------------------------------------------------
__device__ __forceinline__ float darcyA(const float* __restrict__ x,
                                        const float* __restrict__ a,
                                        int i, int j) {
    const float c23 = 2.0f / 3.0f, c16 = 1.0f / 6.0f, c13 = 1.0f / 3.0f;
    float a00 = a[(i - 1) * NCELL + (j - 1)];
    float a01 = a[(i - 1) * NCELL + j];
    float a10 = a[i * NCELL + (j - 1)];
    float a11 = a[i * NCELL + j];
    const float* xm = x + (i - 1) * NGRID;
    const float* xc = x + i * NGRID;
    const float* xp = x + (i + 1) * NGRID;
    return c23 * (a00 + a01 + a10 + a11) * xc[j]
         - c16 * ((a00 + a01) * xm[j] + (a10 + a11) * xp[j]
                + (a00 + a10) * xc[j - 1] + (a01 + a11) * xc[j + 1])
         - c13 * (a00 * xm[j - 1] + a01 * xm[j + 1]
                + a10 * xp[j - 1] + a11 * xp[j + 1]);
}

// mode 0: out = f - A x   (boundary: out = f)
// mode 1: out = x + 0.75*dinv*(f - A x)  (boundary: out = x)
// mode 2: out = A x       (boundary: out = 0)
__global__ void k_stencil(const float* __restrict__ xin,
                          const float* __restrict__ a,
                          const float* __restrict__ f,
                          const float* __restrict__ dinv,
                          float* __restrict__ out, int mode) {
    int b = blockIdx.z;
    int j = blockIdx.x * 16 + threadIdx.x;
    int i = blockIdx.y * 16 + threadIdx.y;
    if (i >= NGRID || j >= NGRID) return;
    const float* xb = xin + (long long)b * N2G;
    const float* ab = a + (long long)b * NCELL * NCELL;
    long long idx = (long long)b * N2G + (long long)i * NGRID + j;
    bool interior = (i >= 1 && i <= NINT && j >= 1 && j <= NINT);
    if (!interior) {
        out[idx] = (mode == 0) ? f[idx] : (mode == 1 ? xb[i * NGRID + j] : 0.0f);
        return;
    }
    float Ax = darcyA(xb, ab, i, j);
    if (mode == 0) {
        out[idx] = f[idx] - Ax;
    } else if (mode == 1) {
        float di = dinv[(long long)b * NI2 + (i - 1) * NINT + (j - 1)];
        out[idx] = xb[i * NGRID + j] + 0.75f * di * (f[idx] - Ax);
    } else {
        out[idx] = Ax;
    }
}

__global__ void k_dinv(const float* __restrict__ a, float* __restrict__ dinv) {
    long long idx = (long long)blockIdx.x * blockDim.x + threadIdx.x;
    if (idx >= (long long)NB * NI2) return;
    int b = (int)(idx / NI2);
    int rem = (int)(idx % NI2);
    int p = rem / NINT, q = rem % NINT;
    const float* ab = a + (long long)b * NCELL * NCELL;
    float s = ab[p * NCELL + q] + ab[p * NCELL + q + 1]
            + ab[(p + 1) * NCELL + q] + ab[(p + 1) * NCELL + q + 1];
    dinv[idx] = 1.0f / ((2.0f / 3.0f) * s);
}

// ---------------------------------------------------------------------------
// Twiddle generation (integer argument reduction -> double sin/cos -> fp32)
// ---------------------------------------------------------------------------
// G[u][n]  = sin(pi*(u-256)*(n+1)/512)              (513 x 511)
// Gt[n][v] = sin(pi*(v-256)*(n+1)/512) * (-1/512^2) (511 x 513)
__global__ void k_gen_dst(float* __restrict__ G, float* __restrict__ Gt) {
    int idx = blockIdx.x * blockDim.x + threadIdx.x;
    if (idx >= NGRID * NINT) return;
    int u = idx / NINT, n = idx % NINT;
    int k = u - 256, nn = n + 1;
    int t = (k * nn) % 1024;
    if (t < 0) t += 1024;
    float s = (float)sin((M_PI / 512.0) * (double)t);
    G[idx] = s;
    Gt[n * NGRID + u] = s * (-1.0f / 262144.0f);
}

// F[y][m]  = exp(-2*pi*i*y*(m-255)/1025)  (511 x 513), Ft = F^T (513 x 511)
__global__ void k_gen_dft(float* __restrict__ Fr, float* __restrict__ Fi,
                          float* __restrict__ Ftr, float* __restrict__ Fti) {
    int idx = blockIdx.x * blockDim.x + threadIdx.x;
    if (idx >= NINT * NGRID) return;
    int y = idx / NGRID, m = idx % NGRID;
    long t = ((long)y * (m - 255)) % 1025;
    if (t < 0) t += 1025;
    double ang = (2.0 * M_PI / 1025.0) * (double)t;
    float cr = (float)cos(ang);
    float ci = (float)(-sin(ang));
    Fr[idx] = cr;
    Fi[idx] = ci;
    Ftr[m * NINT + y] = cr;
    Fti[m * NINT + y] = ci;
}

// ---------------------------------------------------------------------------
// Tiled (complex) GEMM, split-K into PRIVATE partial buffers (no atomics).
// Partial for (batch b, split ks) lives at C + (b*nsplit+ks)*bsC, dense ldc.
// MODE 0: real*real->real ; 1: cplx*cplx->cplx ; 2: cplx*cplx->real-part-only
// 64x64 tile, 16x16 threads, 4x4 per thread, K-tile 16.
// gridDim.z = NB * nsplit.
// ---------------------------------------------------------------------------
template <int MODE>
__global__ __launch_bounds__(256) void k_zgemm(
    const float* __restrict__ Ar, const float* __restrict__ Ai, int lda, long long bsA,
    const float* __restrict__ Br, const float* __restrict__ Bi, int ldb, long long bsB,
    float* __restrict__ Cr, float* __restrict__ Ci, int ldc, long long bsC,
    int M, int N, int K, int nsplit) {
    __shared__ __align__(16) float As_r[16][68];
    __shared__ __align__(16) float Bs_r[16][68];
    __shared__ __align__(16) float As_i[MODE ? 16 : 1][68];
    __shared__ __align__(16) float Bs_i[MODE ? 16 : 1][68];

    int bz = blockIdx.z;
    int b = bz / nsplit;
    int ks = bz % nsplit;
    int kchunk = (K + nsplit - 1) / nsplit;
    int kbeg = ks * kchunk;
    int kend = min(K, kbeg + kchunk);

    Ar += b * bsA; Br += b * bsB;
    if (MODE) { Ai += b * bsA; Bi += b * bsB; }
    long long cbase = ((long long)b * nsplit + ks) * bsC;
    Cr += cbase;
    if (MODE == 1) Ci += cbase;

    int bm = blockIdx.y * 64, bn = blockIdx.x * 64;
    int tid = threadIdx.x;
    int ty = tid >> 4, tx = tid & 15;

    float cr[4][4] = {};
    float cim[4][4] = {};

    for (int kt = kbeg; kt < kend; kt += 16) {
        // stage A tile as [k][m]
        int m = tid >> 2, k0 = (tid & 3) * 4;
        int gm = bm + m;
        #pragma unroll
        for (int c = 0; c < 4; ++c) {
            int gk = kt + k0 + c;
            bool in = (gm < M) && (gk < kend);
            As_r[k0 + c][m] = in ? Ar[(long long)gm * lda + gk] : 0.0f;
            if (MODE) As_i[k0 + c][m] = in ? Ai[(long long)gm * lda + gk] : 0.0f;
        }
        // stage B tile as [k][n]
        int kb = tid >> 4, n0 = (tid & 15) * 4;
        int gk2 = kt + kb;
        #pragma unroll
        for (int c = 0; c < 4; ++c) {
            int gn = bn + n0 + c;
            bool in = (gk2 < kend) && (gn < N);
            Bs_r[kb][n0 + c] = in ? Br[(long long)gk2 * ldb + gn] : 0.0f;
            if (MODE) Bs_i[kb][n0 + c] = in ? Bi[(long long)gk2 * ldb + gn] : 0.0f;
        }
        __syncthreads();
        #pragma unroll
        for (int kk = 0; kk < 16; ++kk) {
            float4 arv = *(const float4*)&As_r[kk][ty * 4];
            float4 brv = *(const float4*)&Bs_r[kk][tx * 4];
            float ar[4] = {arv.x, arv.y, arv.z, arv.w};
            float br[4] = {brv.x, brv.y, brv.z, brv.w};
            if (MODE) {
                float4 aiv = *(const float4*)&As_i[kk][ty * 4];
                float4 biv = *(const float4*)&Bs_i[kk][tx * 4];
                float ai[4] = {aiv.x, aiv.y, aiv.z, aiv.w};
                float bi[4] = {biv.x, biv.y, biv.z, biv.w};
                #pragma unroll
                for (int i2 = 0; i2 < 4; ++i2)
                    #pragma unroll
                    for (int j2 = 0; j2 < 4; ++j2) {
                        cr[i2][j2] += ar[i2] * br[j2] - ai[i2] * bi[j2];
                        if (MODE == 1) cim[i2][j2] += ar[i2] * bi[j2] + ai[i2] * br[j2];
                    }
            } else {
                #pragma unroll
                for (int i2 = 0; i2 < 4; ++i2)
                    #pragma unroll
                    for (int j2 = 0; j2 < 4; ++j2)
                        cr[i2][j2] += ar[i2] * br[j2];
            }
        }
        __syncthreads();
    }

    #pragma unroll
    for (int i2 = 0; i2 < 4; ++i2) {
        int gm = bm + ty * 4 + i2;
        if (gm >= M) continue;
        #pragma unroll
        for (int j2 = 0; j2 < 4; ++j2) {
            int gn = bn + tx * 4 + j2;
            if (gn >= N) continue;
            Cr[(long long)gm * ldc + gn] = cr[i2][j2];
            if (MODE == 1) Ci[(long long)gm * ldc + gn] = cim[i2][j2];
        }
    }
}

// ---------------------------------------------------------------------------
// Sum nsplit dense [M x N] partials -> strided output (row stride ldo).
// Partial for (b,s) at P + (b*nsplit+s)*MN. grid: (x-blocks, NB).
// ---------------------------------------------------------------------------
__global__ void k_reduce(const float* __restrict__ Pr, const float* __restrict__ Pi,
                         float* __restrict__ outR, float* __restrict__ outI,
                         int MN, int N, int ldo, long long bsOut, int nsplit) {
    int b = blockIdx.y;
    for (int idx = blockIdx.x * 256 + threadIdx.x; idx < MN;
         idx += gridDim.x * 256) {
        float sr = 0.0f, si = 0.0f;
        #pragma unroll 4
        for (int s = 0; s < nsplit; ++s) {
            long long o = ((long long)b * nsplit + s) * MN + idx;
            sr += Pr[o];
            if (Pi) si += Pi[o];
        }
        int m = idx / N, n = idx - m * N;
        long long oo = (long long)b * bsOut + (long long)m * ldo + n;
        outR[oo] = sr;
        if (Pi) outI[oo] = si;
    }
}

// ---------------------------------------------------------------------------
// Complex multi-channel 3x3 conv (cross-correlation, zero pad 1), per-batch
// weights. conjt: use w[b][ci][co][q][p] and conjugate (== mcc with conjT(w)).
// ---------------------------------------------------------------------------
template <int CIN, int COUT, bool INC>
__global__ __launch_bounds__(256) void k_mcc(
    const float* __restrict__ xr, const float* __restrict__ xi,
    const float* __restrict__ wr, const float* __restrict__ wi,
    float* __restrict__ yr, float* __restrict__ yi,
    int wb, int ws1, int ws2, int conjt) {
    __shared__ float tile[CIN][2][18][18];
    __shared__ float wl[COUT * CIN * 18];
    int b = blockIdx.z;
    int tid = threadIdx.y * 16 + threadIdx.x;

    for (int idx = tid; idx < COUT * CIN * 9; idx += 256) {
        int co = idx / (CIN * 9);
        int r2 = idx % (CIN * 9);
        int ci = r2 / 9, s = r2 % 9;
        int p = s / 3, q = s % 3;
        int widx = conjt ? (b * wb + ci * ws1 + co * ws2 + q * 3 + p)
                         : (b * wb + co * ws1 + ci * ws2 + p * 3 + q);
        wl[idx * 2] = wr[widx];
        float iv = wi[widx];
        wl[idx * 2 + 1] = conjt ? -iv : iv;
    }
    int ox = blockIdx.x * 16, oy = blockIdx.y * 16;
    for (int idx = tid; idx < CIN * 18 * 18; idx += 256) {
        int ci = idx / 324, r2 = idx % 324;
        int ly = r2 / 18, lx = r2 % 18;
        int gy = oy + ly - 1, gx = ox + lx - 1;
        bool in = (gy >= 0 && gy < NGRID && gx >= 0 && gx < NGRID);
        long long gi = (long long)(b * CIN + ci) * N2G + (long long)gy * NGRID + gx;
        tile[ci][0][ly][lx] = in ? xr[gi] : 0.0f;
        if (INC) tile[ci][1][ly][lx] = in ? xi[gi] : 0.0f;
    }
    __syncthreads();

    int tx = threadIdx.x, ty = threadIdx.y;
    int gx = ox + tx, gy = oy + ty;
    float accr[COUT], acci[COUT];
    #pragma unroll
    for (int co = 0; co < COUT; ++co) { accr[co] = 0.0f; acci[co] = 0.0f; }

    #pragma unroll
    for (int ci = 0; ci < CIN; ++ci)
        #pragma unroll
        for (int p = 0; p < 3; ++p)
            #pragma unroll
            for (int q = 0; q < 3; ++q) {
                float xrv = tile[ci][0][ty + p][tx + q];
                float xiv = INC ? tile[ci][1][ty + p][tx + q] : 0.0f;
                #pragma unroll
                for (int co = 0; co < COUT; ++co) {
                    float wrv = wl[((co * CIN + ci) * 9 + p * 3 + q) * 2];
                    float wiv = wl[((co * CIN + ci) * 9 + p * 3 + q) * 2 + 1];
                    if (INC) {
                        accr[co] += wrv * xrv - wiv * xiv;
                        acci[co] += wrv * xiv + wiv * xrv;
                    } else {
                        accr[co] += wrv * xrv;
                        acci[co] += wiv * xrv;
                    }
                }
            }

    if (gy < NGRID && gx < NGRID) {
        #pragma unroll
        for (int co = 0; co < COUT; ++co) {
            long long gi = (long long)(b * COUT + co) * N2G + (long long)gy * NGRID + gx;
            yr[gi] = accr[co];
            yi[gi] = acci[co];
        }
    }
}

// o *= wt * ik2  (complex multiply by wt, scale by ik2)
__global__ void k_scale(float* __restrict__ or_, float* __restrict__ oi_,
                        const float* __restrict__ wtr, const float* __restrict__ wti) {
    long long idx = (long long)blockIdx.x * blockDim.x + threadIdx.x;
    if (idx >= (long long)NB * N2G) return;
    int pix = (int)(idx % N2G);
    int u = pix / NGRID, v = pix % NGRID;
    int du = u - 256, dv = v - 256;
    float ik2;
    if (du == 0 && dv == 0)
        ik2 = 1.0f;
    else
        ik2 = (float)(1.0 / (9.869604401089358 * (double)(du * du + dv * dv)));
    float xr = or_[idx], xv = oi_[idx];
    float wrv = wtr[idx], wiv = wti[idx];
    or_[idx] = (xr * wrv - xv * wiv) * ik2;
    oi_[idx] = (xr * wiv + xv * wrv) * ik2;
}

// per-batch: red[2b] += sum(r*e), red[2b+1] += sum(Ae*e)
__global__ void k_dot2(const float* __restrict__ r, const float* __restrict__ e,
                       const float* __restrict__ Ae, float* __restrict__ red) {
    int b = blockIdx.y;
    const float* rb = r + (long long)b * N2G;
    const float* eb = e + (long long)b * N2G;
    const float* ab = Ae + (long long)b * N2G;
    float s1 = 0.0f, s2 = 0.0f;
    for (int i = blockIdx.x * blockDim.x + threadIdx.x; i < N2G;
         i += gridDim.x * blockDim.x) {
        float ev = eb[i];
        s1 += rb[i] * ev;
        s2 += ab[i] * ev;
    }
    #pragma unroll
    for (int o = 32; o > 0; o >>= 1) {
        s1 += __shfl_down(s1, o);
        s2 += __shfl_down(s2, o);
    }
    __shared__ float l1[4], l2[4];
    int wid = threadIdx.x >> 6;
    if ((threadIdx.x & 63) == 0) { l1[wid] = s1; l2[wid] = s2; }
    __syncthreads();
    if (threadIdx.x == 0) {
        atomicAdd(&red[2 * b], l1[0] + l1[1] + l1[2] + l1[3]);
        atomicAdd(&red[2 * b + 1], l2[0] + l2[1] + l2[2] + l2[3]);
    }
}

__global__ void k_update(float* __restrict__ x, const float* __restrict__ e,
                         const float* __restrict__ red) {
    long long idx = (long long)blockIdx.x * blockDim.x + threadIdx.x;
    if (idx >= (long long)NB * N2G) return;
    int b = (int)(idx / N2G);
    float alpha = red[2 * b] / red[2 * b + 1];
    x[idx] += alpha * e[idx];
}

__global__ void k_norm(const float* __restrict__ r, const float* __restrict__ f,
                       float* __restrict__ red) {
    float s1 = 0.0f, s2 = 0.0f;
    for (long long i = (long long)blockIdx.x * blockDim.x + threadIdx.x;
         i < (long long)NB * N2G; i += (long long)gridDim.x * blockDim.x) {
        float rv = r[i], fv = f[i];
        s1 += rv * rv;
        s2 += fv * fv;
    }
    #pragma unroll
    for (int o = 32; o > 0; o >>= 1) {
        s1 += __shfl_down(s1, o);
        s2 += __shfl_down(s2, o);
    }
    __shared__ float l1[4], l2[4];
    int wid = threadIdx.x >> 6;
    if ((threadIdx.x & 63) == 0) { l1[wid] = s1; l2[wid] = s2; }
    __syncthreads();
    if (threadIdx.x == 0) {
        atomicAdd(&red[8], l1[0] + l1[1] + l1[2] + l1[3]);
        atomicAdd(&red[9], l2[0] + l2[1] + l2[2] + l2[3]);
    }
}

__global__ void k_final(const float* __restrict__ red, float* __restrict__ out) {
    out[0] = sqrtf(red[8] / red[9]);
}

// ---------------------------------------------------------------------------
extern "C" void kernel_launch(void* const* d_in, const int* in_sizes, int n_in,
                              void* d_out, int out_size, void* d_ws, size_t ws_size,
                              hipStream_t stream) {
    (void)in_sizes; (void)n_in; (void)out_size; (void)ws_size;
    const float* f    = (const float*)d_in[0];
    const float* coef = (const float*)d_in[1];
    const float* w1r  = (const float*)d_in[3];
    const float* w1i  = (const float*)d_in[4];
    const float* w2r  = (const float*)d_in[5];
    const float* w2i  = (const float*)d_in[6];
    const float* w3r  = (const float*)d_in[7];
    const float* w3i  = (const float*)d_in[8];
    const float* wtr  = (const float*)d_in[9];
    const float* wti  = (const float*)d_in[10];
    float* out = (float*)d_out;

    float* ws = (float*)d_ws;
    size_t off = 0;
    auto alloc = [&](long long n) {
        float* p = ws + off;
        off += (size_t)((n + 3) & ~3LL);
        return p;
    };
    float* x0   = alloc((long long)NB * N2G);
    float* x1   = alloc((long long)NB * N2G);
    float* rr   = alloc((long long)NB * N2G);
    float* ee   = alloc((long long)NB * N2G);
    float* rh   = alloc((long long)NB * N2G);
    float* dinv = alloc((long long)NB * NI2);
    // c1r/c1i/c2r double as split-K partial buffers (each = 16*N2G floats
    // = SPLIT(4) * NB(4) * N2G -- exactly enough for 4 dense partials/batch).
    float* c1r  = alloc((long long)NB * 4 * N2G);
    float* c1i  = alloc((long long)NB * 4 * N2G);
    float* c2r  = alloc((long long)NB * 4 * N2G);
    float* c2i  = alloc((long long)NB * 4 * N2G);
    float* or_  = alloc((long long)NB * N2G);
    float* oi_  = alloc((long long)NB * N2G);
    float* t2r  = alloc((long long)NB * NTT);
    float* t2i  = alloc((long long)NB * NTT);
    float* G    = alloc((long long)NGRID * NINT);
    float* Gt   = alloc((long long)NINT * NGRID);
    float* Fr   = alloc((long long)NINT * NGRID);
    float* Fi   = alloc((long long)NINT * NGRID);
    float* Ftr  = alloc((long long)NGRID * NINT);
    float* Fti  = alloc((long long)NGRID * NINT);
    float* red  = alloc(16);
    float* Ae   = x1;  // ping buffer is free when Ae is needed (10 sweeps = even)

    dim3 blk2(16, 16);
    dim3 grdS(33, 33, NB);
    const int SPLIT = 4;  // split-K factor (partial buffers, no atomics)

    hipMemsetAsync(x0, 0, (size_t)NB * N2G * sizeof(float), stream);
    k_dinv<<<dim3((NB * NI2 + 255) / 256), dim3(256), 0, stream>>>(coef, dinv);
    k_gen_dst<<<dim3((NGRID * NINT + 255) / 256), dim3(256), 0, stream>>>(G, Gt);
    k_gen_dft<<<dim3((NINT * NGRID + 255) / 256), dim3(256), 0, stream>>>(Fr, Fi, Ftr, Fti);

    float* xa = x0;
    float* xb = x1;
    for (int step = 0; step < 2; ++step) {
        // 10 weighted-Jacobi sweeps (ping-pong)
        for (int it = 0; it < 10; ++it) {
            k_stencil<<<grdS, blk2, 0, stream>>>(xa, coef, f, dinv, xb, 1);
            float* t = xa; xa = xb; xb = t;
        }
        // residual
        k_stencil<<<grdS, blk2, 0, stream>>>(xa, coef, f, nullptr, rr, 0);

        // ---- H_apply ----
        // rh = -(1/512^2) * G * r_I * G^T (2-D DST == ifft2 of odd extension)
        // t2 = G * r_I : M=513, N=511, K=511
        k_zgemm<0><<<dim3(8, 9, NB * SPLIT), dim3(256), 0, stream>>>(
            G, nullptr, NINT, 0,
            rr + NGRID + 1, nullptr, NGRID, (long long)N2G,
            c1r, nullptr, NINT, (long long)NTT,
            NGRID, NINT, NINT, SPLIT);
        k_reduce<<<dim3(1024, NB), dim3(256), 0, stream>>>(
            c1r, nullptr, t2r, nullptr, NTT, NINT, NINT, (long long)NTT, SPLIT);
        // rh = t2 * Gt : M=513, N=513, K=511
        k_zgemm<0><<<dim3(9, 9, NB * SPLIT), dim3(256), 0, stream>>>(
            t2r, nullptr, NINT, (long long)NTT,
            Gt, nullptr, NGRID, 0,
            c1r, nullptr, NGRID, (long long)N2G,
            NGRID, NGRID, NINT, SPLIT);
        k_reduce<<<dim3(1024, NB), dim3(256), 0, stream>>>(
            c1r, nullptr, rh, nullptr, N2G, NGRID, NGRID, (long long)N2G, SPLIT);
        // forward convs: w1 (1->4), w2 (4->4), w3 (4->1)
        k_mcc<1, 4, false><<<grdS, blk2, 0, stream>>>(rh, nullptr, w1r, w1i, c1r, c1i, 36, 9, 9, 0);
        k_mcc<4, 4, true><<<grdS, blk2, 0, stream>>>(c1r, c1i, w2r, w2i, c2r, c2i, 144, 36, 9, 0);
        k_mcc<4, 1, true><<<grdS, blk2, 0, stream>>>(c2r, c2i, w3r, w3i, or_, oi_, 36, 36, 9, 0);
        // * wt * ik2
        k_scale<<<dim3((NB * N2G + 255) / 256), dim3(256), 0, stream>>>(or_, oi_, wtr, wti);
        // adjoint convs: conjT(w3) (1->4), conjT(w2) (4->4), conjT(w1) (4->1)
        k_mcc<1, 4, true><<<grdS, blk2, 0, stream>>>(or_, oi_, w3r, w3i, c1r, c1i, 36, 36, 9, 1);
        k_mcc<4, 4, true><<<grdS, blk2, 0, stream>>>(c1r, c1i, w2r, w2i, c2r, c2i, 144, 36, 9, 1);
        k_mcc<4, 1, true><<<grdS, blk2, 0, stream>>>(c2r, c2i, w1r, w1i, or_, oi_, 36, 9, 9, 1);
        // e_int = Re( F * O * F^T )  (the 1025-point fft2 of ifftshifted pad)
        // t2 = O * Ft : M=513, N=511, K=513 (complex)  [c1/c2 dead here]
        k_zgemm<1><<<dim3(8, 9, NB * SPLIT), dim3(256), 0, stream>>>(
            or_, oi_, NGRID, (long long)N2G,
            Ftr, Fti, NINT, 0,
            c1r, c1i, NINT, (long long)NTT,
            NGRID, NINT, NGRID, SPLIT);
        k_reduce<<<dim3(1024, NB), dim3(256), 0, stream>>>(
            c1r, c1i, t2r, t2i, NTT, NINT, NINT, (long long)NTT, SPLIT);
        // e_int = Re(F * t2) : M=511, N=511, K=513
        k_zgemm<2><<<dim3(8, 8, NB * SPLIT), dim3(256), 0, stream>>>(
            Fr, Fi, NGRID, 0,
            t2r, t2i, NINT, (long long)NTT,
            c2r, nullptr, NINT, (long long)NI2,
            NINT, NINT, NGRID, SPLIT);
        hipMemsetAsync(ee, 0, (size_t)NB * N2G * sizeof(float), stream);
        k_reduce<<<dim3(1024, NB), dim3(256), 0, stream>>>(
            c2r, nullptr, ee + NGRID + 1, nullptr, NI2, NINT, NGRID, (long long)N2G, SPLIT);

        // Ae = A e ; alpha = (r.e)/(Ae.e) ; x += alpha e
        k_stencil<<<grdS, blk2, 0, stream>>>(ee, coef, nullptr, nullptr, Ae, 2);
        hipMemsetAsync(red, 0, 8 * sizeof(float), stream);
        k_dot2<<<dim3(64, NB), dim3(256), 0, stream>>>(rr, ee, Ae, red);
        k_update<<<dim3((NB * N2G + 255) / 256), dim3(256), 0, stream>>>(xa, ee, red);
    }
    // final relative residual norm
    k_stencil<<<grdS, blk2, 0, stream>>>(xa, coef, f, nullptr, rr, 0);
    hipMemsetAsync(red + 8, 0, 2 * sizeof(float), stream);
    k_norm<<<dim3(256), dim3(256), 0, stream>>>(rr, f, red);
    k_final<<<dim3(1), dim3(1), 0, stream>>>(red, out);
}